// Round 7
// baseline (245.796 us; speedup 1.0000x reference)
//
#include <hip/hip_runtime.h>

#define VOCAB 50000
#define BROWS 4096
#define F 64
#define NCOLS 80            // 64 features + w_hi + w_lo + 14 zero pad
#define NT 5                // n-tiles of 16
#define SPLITS 16
#define NR 98               // K-tiles (of 32) per split
#define KT_TOTAL (SPLITS * NR)            // 1568
#define KPAD (KT_TOTAL * 32)              // 50176
#define RDWORDS (KPAD / 32)               // 1568 packed dwords per row
#define RBYTES  (KPAD / 8)                // 6272 packed bytes per row

#define AS1 __attribute__((address_space(1)))
#define AS3 __attribute__((address_space(3)))

typedef __attribute__((ext_vector_type(4))) float f32x4;
typedef __attribute__((ext_vector_type(8))) short s16x8;

__device__ __forceinline__ unsigned short f2bf(float f) {
    unsigned u = __builtin_bit_cast(unsigned, f);
    unsigned r = (u + 0x7FFFu + ((u >> 16) & 1u)) >> 16;   // round-to-nearest-even
    return (unsigned short)r;
}
__device__ __forceinline__ float bf2f(unsigned short b) {
    unsigned u = ((unsigned)b) << 16;
    return __builtin_bit_cast(float, u);
}

// --- kernel 0: bit-pack x with a PURE LINEAR read sweep ---
// xb dword (b, t) = bits of x[b][32t .. 32t+32), bit j = x[b][32t+j] & 1.
// Consecutive threads read consecutive 128B chunks; stores are coalesced dwords.
__global__ void fm_pack(const int* __restrict__ x, unsigned* __restrict__ xb) {
    const int T = blockIdx.x * 256 + threadIdx.x;       // exactly 4096*1568 threads
    const int b = T / RDWORDS;
    const int t = T - b * RDWORDS;
    const int k0 = t * 32;
    const int* xr = x + (size_t)b * VOCAB + k0;
    unsigned bits = 0;
    if (k0 + 32 <= VOCAB) {                             // fast path (t <= 1561)
        const int4* p = reinterpret_cast<const int4*>(xr);
#pragma unroll
        for (int q = 0; q < 8; ++q) {
            int4 v = p[q];
            bits |= (unsigned)(v.x & 1) << (4 * q);
            bits |= (unsigned)(v.y & 1) << (4 * q + 1);
            bits |= (unsigned)(v.z & 1) << (4 * q + 2);
            bits |= (unsigned)(v.w & 1) << (4 * q + 3);
        }
    } else if (k0 < VOCAB) {                            // t == 1562: 16 valid elems
        for (int j = 0; j < VOCAB - k0; ++j) bits |= (unsigned)(xr[j] & 1) << j;
    }                                                   // t >= 1563: zero pad
    xb[(size_t)b * RDWORDS + t] = bits;
}

// --- kernel 1: w[k] = bias[k] - 0.5*||V[k]||^2 (0 for padded k) ---
__global__ void fm_prep_w(const float* __restrict__ V, const float* __restrict__ bias,
                          float* __restrict__ w) {
    int k = blockIdx.x * blockDim.x + threadIdx.x;
    if (k >= KPAD) return;
    float val = 0.f;
    if (k < VOCAB) {
        const float4* row = reinterpret_cast<const float4*>(V + (size_t)k * F);
        float ss = 0.f;
#pragma unroll
        for (int j = 0; j < F / 4; ++j) {
            float4 v = row[j];
            ss += v.x * v.x + v.y * v.y + v.z * v.z + v.w * v.w;
        }
        val = bias[k] - 0.5f * ss;
    }
    w[k] = val;
}

// --- kernel 2: pack B operand into MFMA 16x16x32 bf16 fragment order ---
// bfrag[(kt*NT + nt)*64 + lane] = uint4 of 8 bf16:
//   elem j = B[kt*32 + (lane>>4)*8 + j][nt*16 + (lane&15)]
// where B[k][n] = V[k][n] (n<64), w_hi[k] (n==64), w_lo[k] (n==65), 0 otherwise.
__global__ void fm_prep_bfrag(const float* __restrict__ V, const float* __restrict__ w,
                              uint4* __restrict__ bfrag) {
    int t = blockIdx.x * blockDim.x + threadIdx.x;
    if (t >= KT_TOTAL * NT * 64) return;
    int lane = t & 63;
    int tile = t >> 6;
    int nt = tile % NT;
    int kt = tile / NT;
    int n = nt * 16 + (lane & 15);
    int kbase = kt * 32 + (lane >> 4) * 8;
    unsigned short o[8];
#pragma unroll
    for (int j = 0; j < 8; ++j) {
        int k = kbase + j;
        float v = 0.f;
        if (k < VOCAB) {
            if (n < F) {
                v = V[(size_t)k * F + n];
            } else if (n == F) {
                v = w[k];                       // f2bf below -> w_hi
            } else if (n == F + 1) {
                float wv = w[k];
                v = wv - bf2f(f2bf(wv));        // residual -> w_lo
            }
        }
        o[j] = f2bf(v);
    }
    uint4 pk;
    pk.x = (unsigned)o[0] | ((unsigned)o[1] << 16);
    pk.y = (unsigned)o[2] | ((unsigned)o[3] << 16);
    pk.z = (unsigned)o[4] | ((unsigned)o[5] << 16);
    pk.w = (unsigned)o[6] | ((unsigned)o[7] << 16);
    bfrag[t] = pk;
}

// --- kernel 3: split-K MFMA GEMM reading PACKED x (R2 structure otherwise) ---
// Per lane per round: ONE byte of xb (L2-resident) -> 8 bf16 A-elems via selects.
// B staged to LDS (double-buffered) via global_load_lds; one __syncthreads/round.
__global__ __launch_bounds__(256, 4) void fm_main(const unsigned char* __restrict__ xb,
                                                  const uint4* __restrict__ bfrag,
                                                  float* __restrict__ part) {
    __shared__ uint4 bbuf[2][NT * 64];        // 2 x 5120 B
    const int bx = blockIdx.x;
    const int split = bx & (SPLITS - 1);      // XCD bx&7 sees only 2 splits
    const int mblock = bx >> 4;
    const int tid = threadIdx.x;
    const int wave = tid >> 6;
    const int lane = tid & 63;
    const int kb = lane >> 4;                 // 0..3
    const int rowA = mblock * 64 + wave * 16 + (lane & 15);
    const int kt0 = split * NR;
    // lane's packed-x stream: byte (kt0+r)*4 + kb of row rowA
    const unsigned char* __restrict__ xp = xb + (size_t)rowA * RBYTES + kb + (size_t)kt0 * 4;
    const int e0 = (wave << 6) + lane;

    auto stage = [&](int rnd) {               // 320 uint4 (one B-tile) -> bbuf[rnd&1]
        const uint4* src = bfrag + (size_t)(kt0 + rnd) * (NT * 64);
        uint4* dst = bbuf[rnd & 1];
        __builtin_amdgcn_global_load_lds((const AS1 void*)(src + e0),
                                         (AS3 void*)(dst + (wave << 6)), 16, 0, 0);
        if (wave == 0)                        // elems 256..319
            __builtin_amdgcn_global_load_lds((const AS1 void*)(src + 256 + lane),
                                             (AS3 void*)(dst + 256), 16, 0, 0);
    };
    auto unpack = [&](unsigned m) -> s16x8 {  // 8 bits -> 8 bf16 in {0,1}
        uint4 apk;
        apk.x = ((m & 1u)   ? 0x3F80u : 0u) | ((m & 2u)   ? 0x3F800000u : 0u);
        apk.y = ((m & 4u)   ? 0x3F80u : 0u) | ((m & 8u)   ? 0x3F800000u : 0u);
        apk.z = ((m & 16u)  ? 0x3F80u : 0u) | ((m & 32u)  ? 0x3F800000u : 0u);
        apk.w = ((m & 64u)  ? 0x3F80u : 0u) | ((m & 128u) ? 0x3F800000u : 0u);
        return __builtin_bit_cast(s16x8, apk);
    };

    f32x4 acc[NT];
#pragma unroll
    for (int nt = 0; nt < NT; ++nt) acc[nt] = (f32x4){0.f, 0.f, 0.f, 0.f};

    stage(0);
    unsigned cb = xp[0];                      // round 0 byte
    __syncthreads();

    for (int r = 0; r < NR; ++r) {
        unsigned nb = 0;
        if (r + 1 < NR) {                     // issue next round: B tile + x byte
            stage(r + 1);
            nb = xp[(r + 1) * 4];
        }
        s16x8 af = unpack(cb);
        const uint4* bb = bbuf[r & 1];
#pragma unroll
        for (int nt = 0; nt < NT; ++nt) {
            s16x8 bf = __builtin_bit_cast(s16x8, bb[nt * 64 + lane]);
            acc[nt] = __builtin_amdgcn_mfma_f32_16x16x32_bf16(af, bf, acc[nt], 0, 0, 0);
        }
        __syncthreads();
        cb = nb;
    }

    // D layout: row = (lane>>4)*4 + r, col = lane&15 (within the 16x16 tile)
    float* __restrict__ p = part + (size_t)split * BROWS * NCOLS;
    int m0 = mblock * 64 + wave * 16 + kb * 4;
    int c0 = lane & 15;
#pragma unroll
    for (int nt = 0; nt < NT; ++nt)
#pragma unroll
        for (int r = 0; r < 4; ++r)
            p[(size_t)(m0 + r) * NCOLS + nt * 16 + c0] = acc[nt][r];
}

// --- kernel 4: reduce splits, square-sum, add linear term ---
__global__ void fm_reduce(const float* __restrict__ part, const float* __restrict__ gbias,
                          float* __restrict__ out) {
    int b = blockIdx.x * 4 + (threadIdx.x >> 6);
    int lane = threadIdx.x & 63;
    float acc = 0.f;
#pragma unroll
    for (int s = 0; s < SPLITS; ++s)
        acc += part[((size_t)s * BROWS + b) * NCOLS + lane];
    float sq = acc * acc;
    float ex = 0.f;
    if (lane < 16)       ex = part[((size_t)lane * BROWS + b) * NCOLS + F];
    else if (lane < 32)  ex = part[((size_t)(lane - 16) * BROWS + b) * NCOLS + F + 1];
#pragma unroll
    for (int off = 32; off; off >>= 1) {
        sq += __shfl_xor(sq, off, 64);
        ex += __shfl_xor(ex, off, 64);
    }
    if (lane == 0) out[b] = gbias[0] + ex + 0.5f * sq;
}

extern "C" void kernel_launch(void* const* d_in, const int* in_sizes, int n_in,
                              void* d_out, int out_size, void* d_ws, size_t ws_size,
                              hipStream_t stream) {
    const int*   x     = (const int*)d_in[0];
    const float* V     = (const float*)d_in[1];
    const float* bias  = (const float*)d_in[2];
    const float* gbias = (const float*)d_in[3];
    float* out = (float*)d_out;

    // workspace layout
    char* ws = (char*)d_ws;
    unsigned* xbw  = (unsigned*)ws;                             // 25,690,112 B
    uint4* bfrag   = (uint4*)(ws + (size_t)BROWS * RBYTES);     //  8,028,160 B
    float* w       = (float*)(ws + (size_t)BROWS * RBYTES + (size_t)KT_TOTAL * NT * 64 * 16);
    float* part    = (float*)(ws + (size_t)BROWS * RBYTES + (size_t)KT_TOTAL * NT * 64 * 16
                              + (size_t)KPAD * 4);              // 20,971,520 B
    // total ~= 54.9 MB

    fm_pack<<<(BROWS * RDWORDS) / 256, 256, 0, stream>>>(x, xbw);
    fm_prep_w<<<(KPAD + 255) / 256, 256, 0, stream>>>(V, bias, w);
    fm_prep_bfrag<<<(KT_TOTAL * NT * 64 + 255) / 256, 256, 0, stream>>>(V, w, bfrag);
    fm_main<<<(BROWS / 64) * SPLITS, 256, 0, stream>>>((const unsigned char*)xbw, bfrag, part);
    fm_reduce<<<BROWS / 4, 256, 0, stream>>>(part, gbias, out);
}

// Round 8
// 226.927 us; speedup vs baseline: 1.0832x; 1.0832x over previous
//
#include <hip/hip_runtime.h>

#define VOCAB 50000
#define BROWS 4096
#define F 64
#define NCOLS 80            // 64 features + w_hi + w_lo + 14 zero pad
#define NT 5                // n-tiles of 16
#define SPLITS 16
#define NR 98               // K-tiles (of 32) per split
#define KT_TOTAL (SPLITS * NR)            // 1568
#define KPAD (KT_TOTAL * 32)              // 50176

#define AS1 __attribute__((address_space(1)))
#define AS3 __attribute__((address_space(3)))

typedef __attribute__((ext_vector_type(4))) float f32x4;
typedef __attribute__((ext_vector_type(8))) short s16x8;

__device__ __forceinline__ unsigned short f2bf(float f) {
    unsigned u = __builtin_bit_cast(unsigned, f);
    unsigned r = (u + 0x7FFFu + ((u >> 16) & 1u)) >> 16;   // round-to-nearest-even
    return (unsigned short)r;
}
__device__ __forceinline__ float bf2f(unsigned short b) {
    unsigned u = ((unsigned)b) << 16;
    return __builtin_bit_cast(float, u);
}

// --- kernel 1: w[k] = bias[k] - 0.5*||V[k]||^2 (0 for padded k) ---
__global__ void fm_prep_w(const float* __restrict__ V, const float* __restrict__ bias,
                          float* __restrict__ w) {
    int k = blockIdx.x * blockDim.x + threadIdx.x;
    if (k >= KPAD) return;
    float val = 0.f;
    if (k < VOCAB) {
        const float4* row = reinterpret_cast<const float4*>(V + (size_t)k * F);
        float ss = 0.f;
#pragma unroll
        for (int j = 0; j < F / 4; ++j) {
            float4 v = row[j];
            ss += v.x * v.x + v.y * v.y + v.z * v.z + v.w * v.w;
        }
        val = bias[k] - 0.5f * ss;
    }
    w[k] = val;
}

// --- kernel 2: pack B operand into MFMA 16x16x32 bf16 fragment order ---
// bfrag[(kt*NT + nt)*64 + lane] = uint4 of 8 bf16:
//   elem j = B[kt*32 + (lane>>4)*8 + j][nt*16 + (lane&15)]
// where B[k][n] = V[k][n] (n<64), w_hi[k] (n==64), w_lo[k] (n==65), 0 otherwise.
__global__ void fm_prep_bfrag(const float* __restrict__ V, const float* __restrict__ w,
                              uint4* __restrict__ bfrag) {
    int t = blockIdx.x * blockDim.x + threadIdx.x;
    if (t >= KT_TOTAL * NT * 64) return;
    int lane = t & 63;
    int tile = t >> 6;
    int nt = tile % NT;
    int kt = tile / NT;
    int n = nt * 16 + (lane & 15);
    int kbase = kt * 32 + (lane >> 4) * 8;
    unsigned short o[8];
#pragma unroll
    for (int j = 0; j < 8; ++j) {
        int k = kbase + j;
        float v = 0.f;
        if (k < VOCAB) {
            if (n < F) {
                v = V[(size_t)k * F + n];
            } else if (n == F) {
                v = w[k];                       // f2bf below -> w_hi
            } else if (n == F + 1) {
                float wv = w[k];
                v = wv - bf2f(f2bf(wv));        // residual -> w_lo
            }
        }
        o[j] = f2bf(v);
    }
    uint4 pk;
    pk.x = (unsigned)o[0] | ((unsigned)o[1] << 16);
    pk.y = (unsigned)o[2] | ((unsigned)o[3] << 16);
    pk.z = (unsigned)o[4] | ((unsigned)o[5] << 16);
    pk.w = (unsigned)o[6] | ((unsigned)o[7] << 16);
    bfrag[t] = pk;
}

// --- kernel 3: split-K MFMA GEMM; triple-buffered LDS stage issued 2 rounds
//     ahead, x prefetched 4 rounds ahead, counted vmcnt(6) (never drains),
//     raw s_barrier. Keeps x(r+1..r+4)+2 stages permanently in flight. ---
__global__ __launch_bounds__(256, 4) void fm_main(const int* __restrict__ x,
                                                  const uint4* __restrict__ bfrag,
                                                  float* __restrict__ part) {
    __shared__ uint4 bbuf[3][NT * 64];        // 3 x 5120 B
    const int bx = blockIdx.x;
    const int split = bx & (SPLITS - 1);
    const int mblock = bx >> 4;
    const int tid = threadIdx.x;
    const int wave = tid >> 6;
    const int lane = tid & 63;
    const int kb = lane >> 4;                 // 0..3
    const int rowA = mblock * 64 + wave * 16 + (lane & 15);
    const int* __restrict__ xrow = x + (size_t)rowA * VOCAB;
    const int kt0 = split * NR;
    const int e0 = (wave << 6) + lane;
    // only block 1023 (row 4095 at split 15) can read past the buffer end;
    // other split-15 blocks read into the next row ({0,1} data) which the
    // zero-padded B rows (k >= VOCAB) null out in the MFMA.
    const bool danger = (bx == (BROWS / 64) * SPLITS - 1);

    // uniform 2 VMEM ops per wave (vmcnt bookkeeping relies on this)
    auto stage = [&](uint4* dst, int rnd) {
        const uint4* src = bfrag + (size_t)(kt0 + rnd) * (NT * 64);
        __builtin_amdgcn_global_load_lds((const AS1 void*)(src + e0),
                                         (AS3 void*)(dst + (wave << 6)), 16, 0, 0);
        if (lane < 16)                        // elems 256..319, 16 lanes per wave
            __builtin_amdgcn_global_load_lds((const AS1 void*)(src + 256 + (wave << 4) + lane),
                                             (AS3 void*)(dst + 256 + (wave << 4)), 16, 0, 0);
    };
    auto prefx = [&](int r, int4& a, int4& b) {   // always 2 VMEM ops
        const int k = (kt0 + r) * 32 + kb * 8;
        if (!(danger && r >= 92)) {
            a = *reinterpret_cast<const int4*>(xrow + k);
            b = *reinterpret_cast<const int4*>(xrow + k + 4);
        } else {                               // block 1023 tail: per-elem guard
            int v[8];
#pragma unroll
            for (int j = 0; j < 8; ++j) v[j] = (k + j < VOCAB) ? xrow[k + j] : 0;
            a = make_int4(v[0], v[1], v[2], v[3]);
            b = make_int4(v[4], v[5], v[6], v[7]);
        }
    };
    auto mk = [&](int4 a0, int4 a1) -> s16x8 {    // x in {0,1}: bf16(1.0)=0x3F80
        uint4 apk;
        apk.x = ((unsigned)a0.x + ((unsigned)a0.y << 16)) * 16256u;
        apk.y = ((unsigned)a0.z + ((unsigned)a0.w << 16)) * 16256u;
        apk.z = ((unsigned)a1.x + ((unsigned)a1.y << 16)) * 16256u;
        apk.w = ((unsigned)a1.z + ((unsigned)a1.w << 16)) * 16256u;
        return __builtin_bit_cast(s16x8, apk);
    };

    f32x4 acc[NT];
#pragma unroll
    for (int nt = 0; nt < NT; ++nt) acc[nt] = (f32x4){0.f, 0.f, 0.f, 0.f};

// Round r: wait stage(r) [7th-newest op: newer = x(r+2),stage(r+1),x(r+3)=6],
// barrier, issue stage(r+2), consume x(r), issue x(r+4), 5 MFMAs.
#define ROUND(r, CBUF, SBUF, CA, CB, W)                                        \
    {                                                                          \
        asm volatile("s_waitcnt vmcnt(" #W ")" ::: "memory");                  \
        __builtin_amdgcn_sched_barrier(0);                                     \
        __builtin_amdgcn_s_barrier();                                          \
        __builtin_amdgcn_sched_barrier(0);                                     \
        if ((r) + 2 < NR) stage(SBUF, (r) + 2);                                \
        s16x8 af = mk(CA, CB);                                                 \
        if ((r) + 4 < NR) prefx((r) + 4, CA, CB);                              \
        _Pragma("unroll")                                                      \
        for (int nt = 0; nt < NT; ++nt) {                                      \
            s16x8 bf = __builtin_bit_cast(s16x8, (CBUF)[nt * 64 + lane]);      \
            acc[nt] = __builtin_amdgcn_mfma_f32_16x16x32_bf16(af, bf,          \
                                                              acc[nt], 0, 0, 0); \
        }                                                                      \
        __builtin_amdgcn_sched_barrier(0);                                     \
    }

    int4 x0a, x0b, x1a, x1b, x2a, x2b, x3a, x3b;
    stage(bbuf[0], 0);
    stage(bbuf[1], 1);
    prefx(0, x0a, x0b);
    prefx(1, x1a, x1b);
    prefx(2, x2a, x2b);
    prefx(3, x3a, x3b);

    for (int g = 0; g < 7; ++g) {             // rounds 0..83
        const int r0 = 12 * g;                // r0 % 3 == 0, r0 % 4 == 0
        ROUND(r0 + 0,  bbuf[0], bbuf[2], x0a, x0b, 6)
        ROUND(r0 + 1,  bbuf[1], bbuf[0], x1a, x1b, 6)
        ROUND(r0 + 2,  bbuf[2], bbuf[1], x2a, x2b, 6)
        ROUND(r0 + 3,  bbuf[0], bbuf[2], x3a, x3b, 6)
        ROUND(r0 + 4,  bbuf[1], bbuf[0], x0a, x0b, 6)
        ROUND(r0 + 5,  bbuf[2], bbuf[1], x1a, x1b, 6)
        ROUND(r0 + 6,  bbuf[0], bbuf[2], x2a, x2b, 6)
        ROUND(r0 + 7,  bbuf[1], bbuf[0], x3a, x3b, 6)
        ROUND(r0 + 8,  bbuf[2], bbuf[1], x0a, x0b, 6)
        ROUND(r0 + 9,  bbuf[0], bbuf[2], x1a, x1b, 6)
        ROUND(r0 + 10, bbuf[1], bbuf[0], x2a, x2b, 6)
        ROUND(r0 + 11, bbuf[2], bbuf[1], x3a, x3b, 6)
    }
    // rounds 84..95 (round 95: prefx(99) skipped at 94 shifts count -> vmcnt(4))
    ROUND(84, bbuf[0], bbuf[2], x0a, x0b, 6)
    ROUND(85, bbuf[1], bbuf[0], x1a, x1b, 6)
    ROUND(86, bbuf[2], bbuf[1], x2a, x2b, 6)
    ROUND(87, bbuf[0], bbuf[2], x3a, x3b, 6)
    ROUND(88, bbuf[1], bbuf[0], x0a, x0b, 6)
    ROUND(89, bbuf[2], bbuf[1], x1a, x1b, 6)
    ROUND(90, bbuf[0], bbuf[2], x2a, x2b, 6)
    ROUND(91, bbuf[1], bbuf[0], x3a, x3b, 6)
    ROUND(92, bbuf[2], bbuf[1], x0a, x0b, 6)
    ROUND(93, bbuf[0], bbuf[2], x1a, x1b, 6)
    ROUND(94, bbuf[1], bbuf[0], x2a, x2b, 6)
    ROUND(95, bbuf[2], bbuf[1], x3a, x3b, 4)

    // round 96: full drain (tail), then 97 (no LDS writes since -> no barrier)
    asm volatile("s_waitcnt vmcnt(0)" ::: "memory");
    __builtin_amdgcn_sched_barrier(0);
    __builtin_amdgcn_s_barrier();
    __builtin_amdgcn_sched_barrier(0);
    {
        s16x8 af = mk(x0a, x0b);              // x(96): slot 0 (loaded at r=92)
#pragma unroll
        for (int nt = 0; nt < NT; ++nt) {
            s16x8 bf = __builtin_bit_cast(s16x8, bbuf[0][nt * 64 + lane]);
            acc[nt] = __builtin_amdgcn_mfma_f32_16x16x32_bf16(af, bf, acc[nt], 0, 0, 0);
        }
    }
    {
        s16x8 af = mk(x1a, x1b);              // x(97): slot 1 (loaded at r=93)
#pragma unroll
        for (int nt = 0; nt < NT; ++nt) {
            s16x8 bf = __builtin_bit_cast(s16x8, bbuf[1][nt * 64 + lane]);
            acc[nt] = __builtin_amdgcn_mfma_f32_16x16x32_bf16(af, bf, acc[nt], 0, 0, 0);
        }
    }
#undef ROUND

    // D layout: row = (lane>>4)*4 + r, col = lane&15 (within the 16x16 tile)
    float* __restrict__ p = part + (size_t)split * BROWS * NCOLS;
    int m0 = mblock * 64 + wave * 16 + kb * 4;
    int c0 = lane & 15;
#pragma unroll
    for (int nt = 0; nt < NT; ++nt)
#pragma unroll
        for (int r = 0; r < 4; ++r)
            p[(size_t)(m0 + r) * NCOLS + nt * 16 + c0] = acc[nt][r];
}

// --- kernel 4: reduce splits, square-sum, add linear term ---
__global__ void fm_reduce(const float* __restrict__ part, const float* __restrict__ gbias,
                          float* __restrict__ out) {
    int b = blockIdx.x * 4 + (threadIdx.x >> 6);
    int lane = threadIdx.x & 63;
    float acc = 0.f;
#pragma unroll
    for (int s = 0; s < SPLITS; ++s)
        acc += part[((size_t)s * BROWS + b) * NCOLS + lane];
    float sq = acc * acc;
    float ex = 0.f;
    if (lane < 16)       ex = part[((size_t)lane * BROWS + b) * NCOLS + F];
    else if (lane < 32)  ex = part[((size_t)(lane - 16) * BROWS + b) * NCOLS + F + 1];
#pragma unroll
    for (int off = 32; off; off >>= 1) {
        sq += __shfl_xor(sq, off, 64);
        ex += __shfl_xor(ex, off, 64);
    }
    if (lane == 0) out[b] = gbias[0] + ex + 0.5f * sq;
}

extern "C" void kernel_launch(void* const* d_in, const int* in_sizes, int n_in,
                              void* d_out, int out_size, void* d_ws, size_t ws_size,
                              hipStream_t stream) {
    const int*   x     = (const int*)d_in[0];
    const float* V     = (const float*)d_in[1];
    const float* bias  = (const float*)d_in[2];
    const float* gbias = (const float*)d_in[3];
    float* out = (float*)d_out;

    // workspace layout
    char* ws = (char*)d_ws;
    uint4* bfrag = (uint4*)ws;                                  // 8,028,160 B
    float* w     = (float*)(ws + (size_t)KT_TOTAL * NT * 64 * 16);
    float* part  = (float*)(ws + (size_t)KT_TOTAL * NT * 64 * 16 + (size_t)KPAD * 4);
    // total: 8,028,160 + 200,704 + 20,971,520 = 29,200,384 B

    fm_prep_w<<<(KPAD + 255) / 256, 256, 0, stream>>>(V, bias, w);
    fm_prep_bfrag<<<(KT_TOTAL * NT * 64 + 255) / 256, 256, 0, stream>>>(V, w, bfrag);
    fm_main<<<(BROWS / 64) * SPLITS, 256, 0, stream>>>(x, bfrag, part);
    fm_reduce<<<BROWS / 4, 256, 0, stream>>>(part, gbias, out);
}